// Round 7
// baseline (6987.757 us; speedup 1.0000x reference)
//
#include <hip/hip_runtime.h>

#define BLOCK 256
#define WHH_STRIDE 76   // halves; 38 words ≡ 6 mod 32 -> ~2-way on b128 (free per m136)

typedef _Float16 half_t;
typedef __attribute__((ext_vector_type(4)))  _Float16 half4;
typedef __attribute__((ext_vector_type(8)))  _Float16 half8;
typedef __attribute__((ext_vector_type(16))) float   float16v;

#define L2E  1.4426950408889634f
#define L2E2 2.8853900817779268f

__device__ __forceinline__ float rcp_(float x) { return __builtin_amdgcn_rcpf(x); }
__device__ __forceinline__ float ex2(float x)  { return __builtin_amdgcn_exp2f(x); }

// ---------------- MLP kernel (~90us, near vector roofline; untouched) ----------------
extern "C" __global__ void __launch_bounds__(BLOCK, 1) mlp_kernel(
    const float* __restrict__ inputs,
    const float* __restrict__ mW0, const float* __restrict__ mb0,
    const float* __restrict__ mW1, const float* __restrict__ mb1,
    const float* __restrict__ mW2, const float* __restrict__ mb2,
    const float* __restrict__ pW, const float* __restrict__ pb,
    float* __restrict__ out, int n)
{
    int b = blockIdx.x * BLOCK + threadIdx.x;
    if (b >= n) return;
    float f0 = inputs[(size_t)b * 18 + 16], f1 = inputs[(size_t)b * 18 + 17];
    float h0[64];
    #pragma unroll
    for (int i = 0; i < 64; ++i)
        h0[i] = fmaxf(fmaf(mW0[2 * i], f0, fmaf(mW0[2 * i + 1], f1, mb0[i])), 0.0f);
    float acc2[32];
    #pragma unroll
    for (int j = 0; j < 32; ++j) acc2[j] = mb2[j];
    #pragma unroll 2
    for (int i = 0; i < 64; ++i) {
        float a = mb1[i];
        #pragma unroll
        for (int k = 0; k < 64; ++k) a = fmaf(mW1[i * 64 + k], h0[k], a);
        a = fmaxf(a, 0.0f);
        #pragma unroll
        for (int j = 0; j < 32; ++j) acc2[j] = fmaf(mW2[j * 64 + i], a, acc2[j]);
    }
    float out0 = pb[0], out1 = pb[1];
    #pragma unroll
    for (int j = 0; j < 32; ++j) {
        out0 = fmaf(pW[256 + j], acc2[j], out0);
        out1 = fmaf(pW[288 + 256 + j], acc2[j], out1);
    }
    ((float2*)out)[b] = make_float2(out0, out1);
}

// ---------------- LSTM (flipped: wave owns 32 batch rows, all 256 gate cols) ----------------
// 32x32x16 f16 MFMA layouts:
//   C/D: col(n)=lane&31, row(m)=(reg&3)+8*(reg>>2)+4*(lane>>5)   [HW-verified m74/m101]
//   A  : A[m=lane&31][k=(lane>>5)*8+i], i=0..7                   [CDNA 32x32x8 pattern, 2xK]
//   B  : B[k=(lane>>5)*8+i][n=lane&31]
// h round-trips through a WAVE-PRIVATE LDS region -> no barriers in the t-loop.
// Whh streamed from LDS as B-frags each step (pre-scaled by log2e; g-gate by 2*log2e).

__device__ __forceinline__ void stage_whh(const float* __restrict__ Whh,
                                          half_t* __restrict__ whh_lds, int tid)
{
    #pragma unroll
    for (int it = 0; it < 16; ++it) {
        int idx4 = tid + it * 256;          // 4096 float4s = 256 rows x 16
        int row  = idx4 >> 4;
        int c4   = idx4 & 15;
        float4 v = ((const float4*)Whh)[idx4];
        float  s = ((row >> 6) == 2) ? L2E2 : L2E;
        half4  h = {(half_t)(v.x * s), (half_t)(v.y * s), (half_t)(v.z * s), (half_t)(v.w * s)};
        *(half4*)&whh_lds[row * WHH_STRIDE + c4 * 4] = h;
    }
}

template <bool LAST>
__device__ __forceinline__ void lstm_step(
    const float* __restrict__ xt,           // xt_lds + t*128
    const half_t* __restrict__ whh_lds,
    half_t* __restrict__ hw,                // wave-private h tile [32][WHH_STRIDE]
    const float wih_s[4][2], const float bias_s[4][2],
    const float ph0[2], const float pc0[2], const float ph1[2], const float pc1[2],
    int w, int l31, int hi,
    float cst[2][16],
    float* __restrict__ wp)                 // [128][2] (LAST only)
{
    // A fragments: h of own 32 rows (written by this wave last step; lgkmcnt only)
    half8 A[4];
    #pragma unroll
    for (int kf = 0; kf < 4; ++kf)
        A[kf] = *(const half8*)&hw[l31 * WHH_STRIDE + kf * 16 + hi * 8];
    float4 x4[4];
    #pragma unroll
    for (int rq = 0; rq < 4; ++rq)
        x4[rq] = *(const float4*)&xt[w * 32 + rq * 8 + hi * 4];   // broadcast within half-wave

    float po0[16], po1[16];
    if (LAST) {
        #pragma unroll
        for (int r = 0; r < 16; ++r) { po0[r] = 0.0f; po1[r] = 0.0f; }
    }

    #pragma unroll
    for (int jt = 0; jt < 2; ++jt) {
        float16v acc[4];
        #pragma unroll
        for (int g = 0; g < 4; ++g) {
            float16v a;
            #pragma unroll
            for (int reg = 0; reg < 16; ++reg)
                a[reg] = fmaf(((const float*)&x4[reg >> 2])[reg & 3], wih_s[g][jt], bias_s[g][jt]);
            #pragma unroll
            for (int kf = 0; kf < 4; ++kf) {
                half8 B = *(const half8*)&whh_lds[(g * 64 + jt * 32 + l31) * WHH_STRIDE + kf * 16 + hi * 8];
                a = __builtin_amdgcn_mfma_f32_32x32x16_f16(A[kf], B, a, 0, 0, 0);
            }
            acc[g] = a;
        }
        #pragma unroll
        for (int reg = 0; reg < 16; ++reg) {
            float Bi  = ex2(acc[0][reg]);
            float Bff = ex2(acc[1][reg]);
            float Bg  = ex2(acc[2][reg]);
            float Bo  = ex2(acc[3][reg]);
            float P   = (1.0f + Bi) * (1.0f + Bg);
            float F   = 1.0f + Bff;
            float t2  = fmaf(Bi, Bg, -Bi);
            float t1  = Bff * cst[jt][reg] * P;
            float cn  = fmaf(t2, F, t1) * rcp_(P * F);
            cst[jt][reg] = cn;
            float Cc  = ex2(cn * L2E2);
            float hv  = fmaf(Bo, Cc, -Bo) * rcp_((1.0f + Bo) * (1.0f + Cc));
            if (LAST) {
                po0[reg] = fmaf(ph0[jt], hv, fmaf(pc0[jt], cn, po0[reg]));
                po1[reg] = fmaf(ph1[jt], hv, fmaf(pc1[jt], cn, po1[reg]));
            } else {
                int m = (reg & 3) + 8 * (reg >> 2) + 4 * hi;
                hw[m * WHH_STRIDE + jt * 32 + l31] = (half_t)hv;
            }
        }
    }

    if (LAST) {
        // reduce over the 32 j-lanes (m is uniform across each 32-half for fixed reg)
        #pragma unroll
        for (int reg = 0; reg < 16; ++reg) {
            #pragma unroll
            for (int s = 1; s < 32; s <<= 1) {
                po0[reg] += __shfl_xor(po0[reg], s, 64);
                po1[reg] += __shfl_xor(po1[reg], s, 64);
            }
        }
        if (l31 == 0) {
            #pragma unroll
            for (int reg = 0; reg < 16; ++reg) {
                int m = w * 32 + (reg & 3) + 8 * (reg >> 2) + 4 * hi;
                wp[m * 2]     += po0[reg];
                wp[m * 2 + 1] += po1[reg];
            }
        }
    }
}

__device__ __forceinline__ void lstm_run(
    const float* __restrict__ Wih, const float* __restrict__ bih, const float* __restrict__ bhh,
    const float* __restrict__ pW, int zbase,
    const half_t* __restrict__ whh_lds, const float* __restrict__ xt,
    half_t* __restrict__ hw, int w, int lane, float* __restrict__ wp)
{
    const int l31 = lane & 31;
    const int hi  = lane >> 5;

    float wih_s[4][2], bias_s[4][2];
    #pragma unroll
    for (int g = 0; g < 4; ++g) {
        float s = (g == 2) ? L2E2 : L2E;
        #pragma unroll
        for (int jt = 0; jt < 2; ++jt) {
            int nn = g * 64 + jt * 32 + l31;
            wih_s[g][jt]  = Wih[nn] * s;
            bias_s[g][jt] = (bih[nn] + bhh[nn]) * s;
        }
    }
    float ph0[2], pc0[2], ph1[2], pc1[2];
    #pragma unroll
    for (int jt = 0; jt < 2; ++jt) {
        int j = jt * 32 + l31;
        ph0[jt] = pW[zbase + j];       pc0[jt] = pW[zbase + 64 + j];
        ph1[jt] = pW[288 + zbase + j]; pc1[jt] = pW[288 + zbase + 64 + j];
    }

    float cst[2][16];

    // --- t = 0 peel: h = c = 0 ---
    {
        float4 x4[4];
        #pragma unroll
        for (int rq = 0; rq < 4; ++rq)
            x4[rq] = *(const float4*)&xt[w * 32 + rq * 8 + hi * 4];
        #pragma unroll
        for (int jt = 0; jt < 2; ++jt) {
            #pragma unroll
            for (int reg = 0; reg < 16; ++reg) {
                float xv = ((const float*)&x4[reg >> 2])[reg & 3];
                float Bi = ex2(fmaf(xv, wih_s[0][jt], bias_s[0][jt]));
                float Bg = ex2(fmaf(xv, wih_s[2][jt], bias_s[2][jt]));
                float Bo = ex2(fmaf(xv, wih_s[3][jt], bias_s[3][jt]));
                float cn = fmaf(Bi, Bg, -Bi) * rcp_((1.0f + Bi) * (1.0f + Bg));
                cst[jt][reg] = cn;
                float Cc = ex2(cn * L2E2);
                float hv = fmaf(Bo, Cc, -Bo) * rcp_((1.0f + Bo) * (1.0f + Cc));
                int m = (reg & 3) + 8 * (reg >> 2) + 4 * hi;
                hw[m * WHH_STRIDE + jt * 32 + l31] = (half_t)hv;
            }
        }
    }

    #pragma unroll 1
    for (int t = 1; t < 7; ++t)
        lstm_step<false>(xt + t * 128, whh_lds, hw, wih_s, bias_s,
                         ph0, pc0, ph1, pc1, w, l31, hi, cst, wp);
    lstm_step<true>(xt + 7 * 128, whh_lds, hw, wih_s, bias_s,
                    ph0, pc0, ph1, pc1, w, l31, hi, cst, wp);
}

// (256,2): combined VGPR budget 256; live estimate ~180. Spill tripwire:
// FETCH/WRITE_SIZE must stay at ~42MB/8MB (R6's (256,3) blew this to 855MB/2.3GB).
extern "C" __global__ void __launch_bounds__(BLOCK, 2) lstm_mfma(
    const float* __restrict__ inputs,
    const float* __restrict__ Wih1, const float* __restrict__ Whh1,
    const float* __restrict__ bih1, const float* __restrict__ bhh1,
    const float* __restrict__ Wih2, const float* __restrict__ Whh2,
    const float* __restrict__ bih2, const float* __restrict__ bhh2,
    const float* __restrict__ pW,
    float* __restrict__ out, int n)
{
    __shared__ half_t whh_lds[256 * WHH_STRIDE];        // 38.0 KB
    __shared__ half_t hbuf[4][32 * WHH_STRIDE];         // 19.0 KB, wave-private tiles
    __shared__ float  xt_lds[16 * 128];                 // 8 KB, x transposed [t][row]
    __shared__ float  wp[128][2];                       // 1 KB projection partials

    const int tid  = threadIdx.x;
    const int w    = tid >> 6;
    const int lane = tid & 63;
    const int base = blockIdx.x * 128;

    wp[tid >> 1][tid & 1] = 0.0f;                       // 256 threads zero 256 floats
    stage_whh(Whh1, whh_lds, tid);
    for (int idx = tid; idx < 128 * 18; idx += BLOCK) {
        int row = idx / 18, c = idx % 18;
        float v = inputs[(size_t)(base + row) * 18 + c];
        if (c < 16) xt_lds[c * 128 + row] = v;
    }
    __syncthreads();

    half_t* hw = &hbuf[w][0];
    lstm_run(Wih1, bih1, bhh1, pW, 0, whh_lds, xt_lds, hw, w, lane, &wp[0][0]);

    __syncthreads();                                    // all waves done reading Whh1
    stage_whh(Whh2, whh_lds, tid);
    __syncthreads();

    lstm_run(Wih2, bih2, bhh2, pW, 128, whh_lds, xt_lds + 8 * 128, hw, w, lane, &wp[0][0]);

    __syncthreads();
    if (tid < 128) {
        int gb = base + tid;
        float2 o = ((float2*)out)[gb];                  // MLP kernel ran first on this stream
        o.x += wp[tid][0];
        o.y += wp[tid][1];
        ((float2*)out)[gb] = o;
    }
}

extern "C" void kernel_launch(void* const* d_in, const int* in_sizes, int n_in,
                              void* d_out, int out_size, void* d_ws, size_t ws_size,
                              hipStream_t stream) {
    const int n = in_sizes[0] / 18;           // 1048576
    mlp_kernel<<<(n + BLOCK - 1) / BLOCK, BLOCK, 0, stream>>>(
        (const float*)d_in[0],
        (const float*)d_in[9],  (const float*)d_in[10],
        (const float*)d_in[11], (const float*)d_in[12],
        (const float*)d_in[13], (const float*)d_in[14],
        (const float*)d_in[15], (const float*)d_in[16],
        (float*)d_out, n);
    lstm_mfma<<<n / 128, BLOCK, 0, stream>>>(
        (const float*)d_in[0],
        (const float*)d_in[1], (const float*)d_in[2],
        (const float*)d_in[3], (const float*)d_in[4],
        (const float*)d_in[5], (const float*)d_in[6],
        (const float*)d_in[7], (const float*)d_in[8],
        (const float*)d_in[15],
        (float*)d_out, n);
}

// Round 8
// 3408.609 us; speedup vs baseline: 2.0500x; 2.0500x over previous
//
#include <hip/hip_runtime.h>

#define BLOCK 256
#define WSTR 72   // whh_lds row stride in halves: 144 B -> 16B-aligned rows for b128; 36 words ≡ 4 mod 32 -> 2-way (free)
#define HSTR 72   // h-tile row stride in halves (same alignment; h-writes are 4-way b16 = ~1.6x on 16 writes, negligible)

typedef _Float16 half_t;
typedef __attribute__((ext_vector_type(4)))  _Float16 half4;
typedef __attribute__((ext_vector_type(8)))  _Float16 half8;
typedef __attribute__((ext_vector_type(4)))  float    float4v;

#define L2E  1.4426950408889634f
#define L2E2 2.8853900817779268f

__device__ __forceinline__ float rcp_(float x) { return __builtin_amdgcn_rcpf(x); }
__device__ __forceinline__ float ex2(float x)  { return __builtin_amdgcn_exp2f(x); }

// ---------------- MLP kernel (~90us; untouched) ----------------
extern "C" __global__ void __launch_bounds__(BLOCK, 1) mlp_kernel(
    const float* __restrict__ inputs,
    const float* __restrict__ mW0, const float* __restrict__ mb0,
    const float* __restrict__ mW1, const float* __restrict__ mb1,
    const float* __restrict__ mW2, const float* __restrict__ mb2,
    const float* __restrict__ pW, const float* __restrict__ pb,
    float* __restrict__ out, int n)
{
    int b = blockIdx.x * BLOCK + threadIdx.x;
    if (b >= n) return;
    float f0 = inputs[(size_t)b * 18 + 16], f1 = inputs[(size_t)b * 18 + 17];
    float h0[64];
    #pragma unroll
    for (int i = 0; i < 64; ++i)
        h0[i] = fmaxf(fmaf(mW0[2 * i], f0, fmaf(mW0[2 * i + 1], f1, mb0[i])), 0.0f);
    float acc2[32];
    #pragma unroll
    for (int j = 0; j < 32; ++j) acc2[j] = mb2[j];
    #pragma unroll 2
    for (int i = 0; i < 64; ++i) {
        float a = mb1[i];
        #pragma unroll
        for (int k = 0; k < 64; ++k) a = fmaf(mW1[i * 64 + k], h0[k], a);
        a = fmaxf(a, 0.0f);
        #pragma unroll
        for (int j = 0; j < 32; ++j) acc2[j] = fmaf(mW2[j * 64 + i], a, acc2[j]);
    }
    float out0 = pb[0], out1 = pb[1];
    #pragma unroll
    for (int j = 0; j < 32; ++j) {
        out0 = fmaf(pW[256 + j], acc2[j], out0);
        out1 = fmaf(pW[288 + 256 + j], acc2[j], out1);
    }
    ((float2*)out)[b] = make_float2(out0, out1);
}

// ---------------- LSTM: barrier-free wave-private design ----------------
// Wave owns 16 batch rows x all 64 h-cols. 16x16x32 f16 MFMA (layouts verified R3-R6):
//   C/D: col(n)=lane&15, row(m)=(lane>>4)*4+reg
//   A  : A[m=lane&15][k=quad*8+i]   B: B[k=quad*8+i][n=lane&15]
// All of Whh (4 gates x 4 col-tiles x 2 k-chunks = 32 half8 = 128 regs) lives in
// registers (expected AGPR: MFMA-only reads). h round-trips through a wave-private
// LDS tile; wave-lockstep ds ordering makes it single-buffered, NO t-loop barriers.

__device__ __forceinline__ void stage_whh(const float* __restrict__ Whh,
                                          half_t* __restrict__ whh_lds, int tid)
{
    #pragma unroll
    for (int it = 0; it < 16; ++it) {
        int idx4 = tid + it * 256;          // 4096 float4s = 256 rows x 16
        int row  = idx4 >> 4;
        int c4   = idx4 & 15;
        float4 v = ((const float4*)Whh)[idx4];
        float  s = ((row >> 6) == 2) ? L2E2 : L2E;   // g-gate rows get 2*log2e
        half4  h = {(half_t)(v.x * s), (half_t)(v.y * s), (half_t)(v.z * s), (half_t)(v.w * s)};
        *(half4*)&whh_lds[row * WSTR + c4 * 4] = h;
    }
}

template <bool LAST>
__device__ __forceinline__ void lstm_step(
    const float* __restrict__ xtw,        // &xt_lds[t*64 + w*16]
    half_t* __restrict__ hw,              // wave-private h tile [16][HSTR]
    const half8 Bf[4][4][2],
    const float wih_s[4][4], const float bias_s[4][4],
    const float* __restrict__ pWz,        // pW + zbase (LAST only)
    int l15, int quad,
    float cst[4][4],
    float po0[4], float po1[4])
{
    half8 A0 = *(const half8*)&hw[l15 * HSTR + quad * 8];
    half8 A1 = *(const half8*)&hw[l15 * HSTR + 32 + quad * 8];
    float4v x4 = *(const float4v*)&xtw[quad * 4];
    #pragma unroll
    for (int jt = 0; jt < 4; ++jt) {
        float4v acc[4];
        #pragma unroll
        for (int g = 0; g < 4; ++g) {
            float4v a;
            #pragma unroll
            for (int reg = 0; reg < 4; ++reg)
                a[reg] = fmaf(x4[reg], wih_s[g][jt], bias_s[g][jt]);
            a = __builtin_amdgcn_mfma_f32_16x16x32_f16(A0, Bf[g][jt][0], a, 0, 0, 0);
            a = __builtin_amdgcn_mfma_f32_16x16x32_f16(A1, Bf[g][jt][1], a, 0, 0, 0);
            acc[g] = a;
        }
        #pragma unroll
        for (int reg = 0; reg < 4; ++reg) {
            float Bi  = ex2(acc[0][reg]);
            float Bff = ex2(acc[1][reg]);
            float Bg  = ex2(acc[2][reg]);
            float Bo  = ex2(acc[3][reg]);
            float P   = (1.0f + Bi) * (1.0f + Bg);
            float F   = 1.0f + Bff;
            float t2  = fmaf(Bi, Bg, -Bi);
            float t1  = Bff * cst[jt][reg] * P;
            float cn  = fmaf(t2, F, t1) * rcp_(P * F);
            cst[jt][reg] = cn;
            float Cc  = ex2(cn * L2E2);
            float hv  = fmaf(Bo, Cc, -Bo) * rcp_((1.0f + Bo) * (1.0f + Cc));
            if (LAST) {
                float ph0 = pWz[jt * 16 + l15],       pc0 = pWz[64 + jt * 16 + l15];
                float ph1 = pWz[288 + jt * 16 + l15], pc1 = pWz[288 + 64 + jt * 16 + l15];
                po0[reg] = fmaf(ph0, hv, fmaf(pc0, cn, po0[reg]));
                po1[reg] = fmaf(ph1, hv, fmaf(pc1, cn, po1[reg]));
            } else {
                hw[(quad * 4 + reg) * HSTR + jt * 16 + l15] = (half_t)hv;
            }
        }
    }
}

__device__ __forceinline__ void lstm_run(
    const float* __restrict__ Wih, const float* __restrict__ bih, const float* __restrict__ bhh,
    const half_t* __restrict__ whh_lds,
    const float* __restrict__ xt,          // &xt_lds[run*8*64]
    half_t* __restrict__ hw,
    const float* __restrict__ pWz,
    int w, int l15, int quad,
    float po0[4], float po1[4])
{
    // Bf: 32 half8 = 128 regs, MFMA-only reads -> expected AGPR placement
    half8 Bf[4][4][2];
    float wih_s[4][4], bias_s[4][4];
    #pragma unroll
    for (int g = 0; g < 4; ++g) {
        const float s = (g == 2) ? L2E2 : L2E;
        #pragma unroll
        for (int jt = 0; jt < 4; ++jt) {
            const int n = g * 64 + jt * 16 + l15;
            Bf[g][jt][0] = *(const half8*)&whh_lds[n * WSTR + quad * 8];
            Bf[g][jt][1] = *(const half8*)&whh_lds[n * WSTR + 32 + quad * 8];
            wih_s[g][jt]  = Wih[n] * s;
            bias_s[g][jt] = (bih[n] + bhh[n]) * s;
        }
    }
    float cst[4][4];
    // --- t = 0 peel: h = c = 0 ---
    {
        float4v x4 = *(const float4v*)&xt[w * 16 + quad * 4];
        #pragma unroll
        for (int jt = 0; jt < 4; ++jt) {
            #pragma unroll
            for (int reg = 0; reg < 4; ++reg) {
                float xv = x4[reg];
                float Bi = ex2(fmaf(xv, wih_s[0][jt], bias_s[0][jt]));
                float Bg = ex2(fmaf(xv, wih_s[2][jt], bias_s[2][jt]));
                float Bo = ex2(fmaf(xv, wih_s[3][jt], bias_s[3][jt]));
                float cn = fmaf(Bi, Bg, -Bi) * rcp_((1.0f + Bi) * (1.0f + Bg));
                cst[jt][reg] = cn;
                float Cc = ex2(cn * L2E2);
                float hv = fmaf(Bo, Cc, -Bo) * rcp_((1.0f + Bo) * (1.0f + Cc));
                hw[(quad * 4 + reg) * HSTR + jt * 16 + l15] = (half_t)hv;
            }
        }
    }
    #pragma unroll 1
    for (int t = 1; t < 7; ++t)
        lstm_step<false>(xt + t * 64 + w * 16, hw, Bf, wih_s, bias_s, pWz, l15, quad, cst, po0, po1);
    lstm_step<true>(xt + 7 * 64 + w * 16, hw, Bf, wih_s, bias_s, pWz, l15, quad, cst, po0, po1);
}

// (256,2): combined budget 256/wave. Estimate: Bf 128 (AGPR) + acc 16 + ~110 VGPR ≈ 240.
// Spill tripwire: FETCH/WRITE must stay ~45MB/8MB.
extern "C" __global__ void __launch_bounds__(BLOCK, 2) lstm_mfma(
    const float* __restrict__ inputs,
    const float* __restrict__ Wih1, const float* __restrict__ Whh1,
    const float* __restrict__ bih1, const float* __restrict__ bhh1,
    const float* __restrict__ Wih2, const float* __restrict__ Whh2,
    const float* __restrict__ bih2, const float* __restrict__ bhh2,
    const float* __restrict__ pW,
    float* __restrict__ out, int n)
{
    __shared__ half_t whh_lds[256 * WSTR];   // 36 KB (dead after Bf build; restaged per run)
    __shared__ half_t hbuf[4][16 * HSTR];    // 9 KB wave-private h tiles
    __shared__ float  xt_lds[16 * 64];       // 4 KB x transposed [t][row]

    const int tid  = threadIdx.x;
    const int w    = tid >> 6;
    const int lane = tid & 63;
    const int l15  = lane & 15;
    const int quad = lane >> 4;
    const int base = blockIdx.x * 64;

    stage_whh(Whh1, whh_lds, tid);
    for (int idx = tid; idx < 64 * 18; idx += BLOCK) {
        int row = idx / 18, c = idx % 18;
        float v = inputs[(size_t)(base + row) * 18 + c];
        if (c < 16) xt_lds[c * 64 + row] = v;
    }
    __syncthreads();

    half_t* hw = &hbuf[w][0];
    float po0[4] = {0, 0, 0, 0}, po1[4] = {0, 0, 0, 0};

    lstm_run(Wih1, bih1, bhh1, whh_lds, xt_lds,          hw, pW,       w, l15, quad, po0, po1);
    __syncthreads();                        // all waves done with Whh1 frags? (Bf in regs; this guards whh_lds reuse)
    stage_whh(Whh2, whh_lds, tid);
    __syncthreads();
    lstm_run(Wih2, bih2, bhh2, whh_lds, xt_lds + 8 * 64, hw, pW + 128, w, l15, quad, po0, po1);

    // reduce over the 16 col-lanes; rows m = quad*4 + reg
    #pragma unroll
    for (int reg = 0; reg < 4; ++reg) {
        #pragma unroll
        for (int s = 1; s < 16; s <<= 1) {
            po0[reg] += __shfl_xor(po0[reg], s, 64);
            po1[reg] += __shfl_xor(po1[reg], s, 64);
        }
    }
    if (l15 == 0) {
        #pragma unroll
        for (int reg = 0; reg < 4; ++reg) {
            int gb = base + w * 16 + quad * 4 + reg;
            float2 o = ((float2*)out)[gb];   // MLP kernel ran first on this stream
            o.x += po0[reg];
            o.y += po1[reg];
            ((float2*)out)[gb] = o;
        }
    }
}

extern "C" void kernel_launch(void* const* d_in, const int* in_sizes, int n_in,
                              void* d_out, int out_size, void* d_ws, size_t ws_size,
                              hipStream_t stream) {
    const int n = in_sizes[0] / 18;           // 1048576
    mlp_kernel<<<(n + BLOCK - 1) / BLOCK, BLOCK, 0, stream>>>(
        (const float*)d_in[0],
        (const float*)d_in[9],  (const float*)d_in[10],
        (const float*)d_in[11], (const float*)d_in[12],
        (const float*)d_in[13], (const float*)d_in[14],
        (const float*)d_in[15], (const float*)d_in[16],
        (float*)d_out, n);
    lstm_mfma<<<n / 64, BLOCK, 0, stream>>>(
        (const float*)d_in[0],
        (const float*)d_in[1], (const float*)d_in[2],
        (const float*)d_in[3], (const float*)d_in[4],
        (const float*)d_in[5], (const float*)d_in[6],
        (const float*)d_in[7], (const float*)d_in[8],
        (const float*)d_in[15],
        (float*)d_out, n);
}